// Round 12
// baseline (126.661 us; speedup 1.0000x reference)
//
#include <hip/hip_runtime.h>

#define BB 2
#define NN 256
#define CC 256

__device__ __forceinline__ float dot4acc(float4 e, float4 w, float s) {
    s = fmaf(e.x, w.x, s); s = fmaf(e.y, w.y, s);
    s = fmaf(e.z, w.z, s); s = fmaf(e.w, w.w, s);
    return s;
}

// async global->LDS DMA, 16 bytes per lane (wave-uniform LDS base + lane*16)
#define GLL(gaddr, laddr)                                                     \
    __builtin_amdgcn_global_load_lds(                                         \
        (const __attribute__((address_space(1))) void*)(gaddr),               \
        (__attribute__((address_space(3))) void*)(laddr), 16, 0, 0)

// stage one 8-row (8 KB) tile with 4 waves: wave w fills rows 2w, 2w+1
#define STAGE8(B, SRC, TT)                                                    \
    do {                                                                      \
        const float* _g = (SRC) + (size_t)(TT) * 2048;                        \
        GLL(_g + (w * 2) * 256 + l * 4,     (B) + (w * 2) * 256);             \
        GLL(_g + (w * 2 + 1) * 256 + l * 4, (B) + (w * 2 + 1) * 256);         \
    } while (0)

// ---------------------------------------------------------------------------
// K1: fused q/k/v projections.  rows 0..511 = q (B*N), 512..1023 = k, 1024..1535 = v
// ---------------------------------------------------------------------------
__global__ __launch_bounds__(256) void proj_gemm(
    const float* __restrict__ q_tok, const float* __restrict__ k_tok, const float* __restrict__ v_tok,
    const float* __restrict__ Wq, const float* __restrict__ bq,
    const float* __restrict__ Wk, const float* __restrict__ bk,
    const float* __restrict__ Wv, const float* __restrict__ bv,
    float* __restrict__ out)
{
    const int row0 = blockIdx.x * 64;
    const int col0 = blockIdx.y * 64;
    const int seg  = row0 >> 9;
    const float* A    = seg == 0 ? q_tok : (seg == 1 ? k_tok : v_tok);
    const float* W    = seg == 0 ? Wq    : (seg == 1 ? Wk    : Wv);
    const float* bias = seg == 0 ? bq    : (seg == 1 ? bk    : bv);
    const int ar0 = row0 & 511;

    __shared__ float As[64][17];
    __shared__ float Bs[16][68];
    const int t  = threadIdx.x;
    const int tr = t >> 4, tc = t & 15;
    float acc[4][4] = {};

    const int sr  = t >> 2, sk4 = (t & 3) << 2;
    const int bkr = t >> 4, bj4 = (t & 15) << 2;

    for (int k0 = 0; k0 < 256; k0 += 16) {
        float4 a4 = *reinterpret_cast<const float4*>(&A[(ar0 + sr) * 256 + k0 + sk4]);
        float4 b4 = *reinterpret_cast<const float4*>(&W[(k0 + bkr) * 256 + col0 + bj4]);
        As[sr][sk4 + 0] = a4.x; As[sr][sk4 + 1] = a4.y; As[sr][sk4 + 2] = a4.z; As[sr][sk4 + 3] = a4.w;
        Bs[bkr][bj4 + 0] = b4.x; Bs[bkr][bj4 + 1] = b4.y; Bs[bkr][bj4 + 2] = b4.z; Bs[bkr][bj4 + 3] = b4.w;
        __syncthreads();
        #pragma unroll
        for (int k = 0; k < 16; ++k) {
            float a[4], bbv[4];
            #pragma unroll
            for (int i = 0; i < 4; ++i) a[i] = As[tr * 4 + i][k];
            #pragma unroll
            for (int j = 0; j < 4; ++j) bbv[j] = Bs[k][tc * 4 + j];
            #pragma unroll
            for (int i = 0; i < 4; ++i)
                #pragma unroll
                for (int j = 0; j < 4; ++j)
                    acc[i][j] = fmaf(a[i], bbv[j], acc[i][j]);
        }
        __syncthreads();
    }
    #pragma unroll
    for (int i = 0; i < 4; ++i) {
        const int r = row0 + tr * 4 + i;
        #pragma unroll
        for (int j = 0; j < 4; ++j) {
            const int cj = col0 + tc * 4 + j;
            out[r * 256 + cj] = acc[i][j] + bias[cj];
        }
    }
}

// ---------------------------------------------------------------------------
// K2: qW[bn][h][d] = sum_c qp[bn][h*64+c] * Wqk[d][h*64+c]
// ---------------------------------------------------------------------------
__global__ __launch_bounds__(256) void qw_gemm(
    const float* __restrict__ qp, const float* __restrict__ Wqk, float* __restrict__ qW)
{
    const int h    = blockIdx.z;
    const int row0 = blockIdx.x * 64;
    const int d0   = blockIdx.y * 64;
    __shared__ float As[64][17];
    __shared__ float Bs[16][68];
    const int t  = threadIdx.x;
    const int tr = t >> 4, tc = t & 15;
    float acc[4][4] = {};
    const int sr = t >> 2, sc4 = (t & 3) << 2;

    for (int k0 = 0; k0 < 64; k0 += 16) {
        float4 a4 = *reinterpret_cast<const float4*>(&qp[(row0 + sr) * 256 + h * 64 + k0 + sc4]);
        float4 b4 = *reinterpret_cast<const float4*>(&Wqk[(d0 + sr) * 256 + h * 64 + k0 + sc4]);
        As[sr][sc4 + 0] = a4.x; As[sr][sc4 + 1] = a4.y; As[sr][sc4 + 2] = a4.z; As[sr][sc4 + 3] = a4.w;
        Bs[sc4 + 0][sr] = b4.x; Bs[sc4 + 1][sr] = b4.y; Bs[sc4 + 2][sr] = b4.z; Bs[sc4 + 3][sr] = b4.w;
        __syncthreads();
        #pragma unroll
        for (int k = 0; k < 16; ++k) {
            float a[4], bbv[4];
            #pragma unroll
            for (int i = 0; i < 4; ++i) a[i] = As[tr * 4 + i][k];
            #pragma unroll
            for (int j = 0; j < 4; ++j) bbv[j] = Bs[k][tc * 4 + j];
            #pragma unroll
            for (int i = 0; i < 4; ++i)
                #pragma unroll
                for (int j = 0; j < 4; ++j)
                    acc[i][j] = fmaf(a[i], bbv[j], acc[i][j]);
        }
        __syncthreads();
    }
    #pragma unroll
    for (int i = 0; i < 4; ++i)
        #pragma unroll
        for (int j = 0; j < 4; ++j)
            qW[((row0 + tr * 4 + i) * 4 + h) * 256 + d0 + tc * 4 + j] = acc[i][j];
}

// ---------------------------------------------------------------------------
// K3: Sqk[((b*4+h)*256+n)*256+m] = sum_c q[b,n,h*64+c] * k[b,m,h*64+c]  (raw)
// ---------------------------------------------------------------------------
__global__ __launch_bounds__(256) void qk_gemm(
    const float* __restrict__ qkvp, float* __restrict__ Sqk)
{
    const int bh = blockIdx.z;
    const int b  = bh >> 2, h = bh & 3;
    const int n0 = blockIdx.x * 64;
    const int m0 = blockIdx.y * 64;
    __shared__ float As[64][17];
    __shared__ float Bs[16][68];
    const int t  = threadIdx.x;
    const int tr = t >> 4, tc = t & 15;
    float acc[4][4] = {};
    const int sr = t >> 2, sc4 = (t & 3) << 2;

    for (int k0 = 0; k0 < 64; k0 += 16) {
        float4 a4 = *reinterpret_cast<const float4*>(&qkvp[(size_t)(b * 256 + n0 + sr) * 256 + h * 64 + k0 + sc4]);
        float4 b4 = *reinterpret_cast<const float4*>(&qkvp[(size_t)(512 + b * 256 + m0 + sr) * 256 + h * 64 + k0 + sc4]);
        As[sr][sc4 + 0] = a4.x; As[sr][sc4 + 1] = a4.y; As[sr][sc4 + 2] = a4.z; As[sr][sc4 + 3] = a4.w;
        Bs[sc4 + 0][sr] = b4.x; Bs[sc4 + 1][sr] = b4.y; Bs[sc4 + 2][sr] = b4.z; Bs[sc4 + 3][sr] = b4.w;
        __syncthreads();
        #pragma unroll
        for (int k = 0; k < 16; ++k) {
            float a[4], bbv[4];
            #pragma unroll
            for (int i = 0; i < 4; ++i) a[i] = As[tr * 4 + i][k];
            #pragma unroll
            for (int j = 0; j < 4; ++j) bbv[j] = Bs[k][tc * 4 + j];
            #pragma unroll
            for (int i = 0; i < 4; ++i)
                #pragma unroll
                for (int j = 0; j < 4; ++j)
                    acc[i][j] = fmaf(a[i], bbv[j], acc[i][j]);
        }
        __syncthreads();
    }
    #pragma unroll
    for (int i = 0; i < 4; ++i)
        #pragma unroll
        for (int j = 0; j < 4; ++j)
            Sqk[(size_t)((b * 4 + h) * 256 + n0 + tr * 4 + i) * 256 + m0 + tc * 4 + j] = acc[i][j];
}

// ---------------------------------------------------------------------------
// K4: stream_kernel — block (bn, quarter q) owns 64 rows.  DMA-pipelined
// qk pass -> block-local softmax stats -> DMA-pipelined qv pass -> block
// A-partial.  Small LDS (~23 KB) so ~6 blocks/CU (24 waves/CU).
// Outputs: Sg raw scores, stats (mx,sum per bn,q,h), Aq partials.
// ---------------------------------------------------------------------------
__global__ __launch_bounds__(256, 6) void stream_kernel(
    const float* __restrict__ qk_emb, const float* __restrict__ qv_emb,
    const float* __restrict__ qW, const float* __restrict__ Sqk,
    float* __restrict__ Sg, float* __restrict__ stats, float* __restrict__ Aq)
{
    const int bn = blockIdx.x;
    const int q  = blockIdx.y;
    const int b  = bn >> 8, n = bn & 255;
    const int t  = threadIdx.x;
    const int w  = t >> 6, l = t & 63;

    __shared__ __align__(16) float buf0[2048];    // 8 KB tile A / later Ap[8][256]
    __shared__ __align__(16) float buf1[2048];    // 8 KB tile B
    __shared__ __align__(16) float qWs[1024];     // [h][d]
    __shared__ __align__(16) float SqkL[256];     // [h][64] this quarter
    __shared__ __align__(16) float Ssc[256];      // [h][64] pair scores
    __shared__ __align__(16) float attn_e[256];   // [h][64] unnormalized e

    const float* qkb = qk_emb + (size_t)bn * 65536 + (size_t)q * 16384;
    const float* qvb = qv_emb + (size_t)bn * 65536 + (size_t)q * 16384;

    // prologue: issue qk tile0 DMA, stage qW + Sqk quarter
    STAGE8(buf0, qkb, 0);
    *reinterpret_cast<float4*>(&qWs[t * 4]) =
        *reinterpret_cast<const float4*>(&qW[(size_t)bn * 1024 + t * 4]);
    {
        const int h = t >> 6, mi = t & 63;
        SqkL[t] = Sqk[(size_t)((b * 4 + h) * 256 + n) * 256 + q * 64 + mi];
    }
    __syncthreads();

    // qk-pass roles: rowg = w>>1 (rows 4rowg..4rowg+3 via lr), head pair hp = w&1
    const int lq = l & 15, lr = l >> 4;
    const int rloc = (w >> 1) * 4 + lr;          // row 0..7 within tile
    const int h0 = (w & 1) * 2, h1 = h0 + 1;

    float4 qr0[4], qr1[4];
    #pragma unroll
    for (int c = 0; c < 4; ++c) {
        qr0[c] = *reinterpret_cast<const float4*>(&qWs[h0 * 256 + c * 64 + lq * 4]);
        qr1[c] = *reinterpret_cast<const float4*>(&qWs[h1 * 256 + c * 64 + lq * 4]);
    }

    // ---- qk stream: 8 tiles of 8 rows, double-buffered DMA ----
    for (int tt = 0; tt < 8; ++tt) {
        float* cur = (tt & 1) ? buf1 : buf0;
        float* nxt = (tt & 1) ? buf0 : buf1;
        if (tt < 7) STAGE8(nxt, qkb, tt + 1);

        const float* er = cur + rloc * 256 + lq * 4;
        const float4 e0 = *reinterpret_cast<const float4*>(er);
        const float4 e1 = *reinterpret_cast<const float4*>(er + 64);
        const float4 e2 = *reinterpret_cast<const float4*>(er + 128);
        const float4 e3 = *reinterpret_cast<const float4*>(er + 192);
        float s0 = 0.f, s1 = 0.f;
        s0 = dot4acc(e0, qr0[0], s0); s0 = dot4acc(e1, qr0[1], s0);
        s0 = dot4acc(e2, qr0[2], s0); s0 = dot4acc(e3, qr0[3], s0);
        s1 = dot4acc(e0, qr1[0], s1); s1 = dot4acc(e1, qr1[1], s1);
        s1 = dot4acc(e2, qr1[2], s1); s1 = dot4acc(e3, qr1[3], s1);
        s0 += __shfl_xor(s0, 1); s1 += __shfl_xor(s1, 1);
        s0 += __shfl_xor(s0, 2); s1 += __shfl_xor(s1, 2);
        s0 += __shfl_xor(s0, 4); s1 += __shfl_xor(s1, 4);
        s0 += __shfl_xor(s0, 8); s1 += __shfl_xor(s1, 8);
        if (lq == 0) {
            const int m = tt * 8 + rloc;
            Ssc[h0 * 64 + m] = s0;
            Ssc[h1 * 64 + m] = s1;
        }
        __syncthreads();
    }

    // prefetch qv tile0 (buf0 free: last qk tile used buf1)
    STAGE8(buf0, qvb, 0);

    // ---- block-local softmax stats: wave w = head w, lane l = local row ----
    {
        const float sc = (Ssc[w * 64 + l] + SqkL[w * 64 + l]) * 0.125f;
        float mx = sc;
        #pragma unroll
        for (int mask = 32; mask >= 1; mask >>= 1) mx = fmaxf(mx, __shfl_xor(mx, mask));
        const float e = __expf(sc - mx);
        attn_e[w * 64 + l] = e;
        float sm = e;
        #pragma unroll
        for (int mask = 32; mask >= 1; mask >>= 1) sm += __shfl_xor(sm, mask);
        Sg[(size_t)((b * 4 + w) * 256 + n) * 256 + q * 64 + l] = sc;
        if (l == 0) {
            const int si = ((bn * 4 + q) * 4 + w) * 2;
            stats[si] = mx;
            stats[si + 1] = sm;
        }
    }
    __syncthreads();   // attn_e visible; qv tile0 DMA drained

    // ---- qv stream: 8 tiles; wave w does rows {w, w+4}; lane owns d = 4l ----
    float4 acc[4];
    #pragma unroll
    for (int hh = 0; hh < 4; ++hh) acc[hh] = make_float4(0.f, 0.f, 0.f, 0.f);

    for (int tt = 0; tt < 8; ++tt) {
        float* cur = (tt & 1) ? buf1 : buf0;
        float* nxt = (tt & 1) ? buf0 : buf1;
        if (tt < 7) STAGE8(nxt, qvb, tt + 1);

        const float4 f0 = *reinterpret_cast<const float4*>(&cur[w * 256 + l * 4]);
        const float4 f1 = *reinterpret_cast<const float4*>(&cur[(w + 4) * 256 + l * 4]);
        const int m0 = tt * 8 + w, m1 = tt * 8 + w + 4;
        #pragma unroll
        for (int hh = 0; hh < 4; ++hh) {
            const float a0 = attn_e[hh * 64 + m0];
            const float a1 = attn_e[hh * 64 + m1];
            acc[hh].x = fmaf(a0, f0.x, acc[hh].x); acc[hh].y = fmaf(a0, f0.y, acc[hh].y);
            acc[hh].z = fmaf(a0, f0.z, acc[hh].z); acc[hh].w = fmaf(a0, f0.w, acc[hh].w);
            acc[hh].x = fmaf(a1, f1.x, acc[hh].x); acc[hh].y = fmaf(a1, f1.y, acc[hh].y);
            acc[hh].z = fmaf(a1, f1.z, acc[hh].z); acc[hh].w = fmaf(a1, f1.w, acc[hh].w);
        }
        __syncthreads();
    }

    // ---- reduce 4 wave partials via buf0 as Ap[8][256] ----
    float* Ap = buf0;
    if (w < 2) {
        #pragma unroll
        for (int hh = 0; hh < 4; ++hh)
            *reinterpret_cast<float4*>(&Ap[(w * 4 + hh) * 256 + l * 4]) = acc[hh];
    }
    __syncthreads();
    if (w >= 2) {
        #pragma unroll
        for (int hh = 0; hh < 4; ++hh) {
            float4* p = reinterpret_cast<float4*>(&Ap[((w - 2) * 4 + hh) * 256 + l * 4]);
            float4 o = *p;
            o.x += acc[hh].x; o.y += acc[hh].y; o.z += acc[hh].z; o.w += acc[hh].w;
            *p = o;
        }
    }
    __syncthreads();
    #pragma unroll
    for (int i = 0; i < 4; ++i) {
        const int idx = t + i * 256;
        const int hh = idx >> 8, d = idx & 255;
        Aq[((size_t)(bn * 4 + q) * 4 + hh) * 256 + d] = Ap[hh * 256 + d] + Ap[(4 + hh) * 256 + d];
    }
}

// ---------------------------------------------------------------------------
// K5: merge_kernel — per bn: exact cross-quarter softmax merge; writes
// normalized attn (d_out) and Afull = sum_q Aq * scale.
// ---------------------------------------------------------------------------
__global__ __launch_bounds__(256) void merge_kernel(
    const float* __restrict__ Sg, const float* __restrict__ stats,
    const float* __restrict__ Aq, float* __restrict__ attn_out,
    float* __restrict__ Afull)
{
    const int bn = blockIdx.x;
    const int b = bn >> 8, n = bn & 255;
    const int t = threadIdx.x;
    const int h = t >> 6, mi = t & 63;

    float mx[4], sm[4];
    #pragma unroll
    for (int qq = 0; qq < 4; ++qq) {
        const int si = ((bn * 4 + qq) * 4 + h) * 2;
        mx[qq] = stats[si];
        sm[qq] = stats[si + 1];
    }
    float mg = fmaxf(fmaxf(mx[0], mx[1]), fmaxf(mx[2], mx[3]));
    float sg = 0.f;
    #pragma unroll
    for (int qq = 0; qq < 4; ++qq) sg += sm[qq] * __expf(mx[qq] - mg);
    const float inv = 1.f / sg;

    const size_t rowbase = (size_t)((b * 4 + h) * 256 + n) * 256;
    #pragma unroll
    for (int qq = 0; qq < 4; ++qq) {
        const int m = qq * 64 + mi;
        attn_out[rowbase + m] = __expf(Sg[rowbase + m] - mg) * inv;
    }

    float4 af = make_float4(0.f, 0.f, 0.f, 0.f);
    #pragma unroll
    for (int qq = 0; qq < 4; ++qq) {
        const float scl = __expf(mx[qq] - mg) * inv;
        const float4 v = *reinterpret_cast<const float4*>(
            &Aq[((size_t)(bn * 4 + qq) * 4 + h) * 256 + mi * 4]);
        af.x = fmaf(v.x, scl, af.x); af.y = fmaf(v.y, scl, af.y);
        af.z = fmaf(v.z, scl, af.z); af.w = fmaf(v.w, scl, af.w);
    }
    *reinterpret_cast<float4*>(&Afull[(size_t)bn * 1024 + h * 256 + mi * 4]) = af;
}

// ---------------------------------------------------------------------------
// K6: out_gemm — hidden = attn@v + Afull@Wqv + bqv  (verified in mega5 era)
// ---------------------------------------------------------------------------
__global__ __launch_bounds__(256) void out_gemm(
    const float* __restrict__ qkvp, const float* __restrict__ attn,
    const float* __restrict__ Afull, const float* __restrict__ Wqv,
    const float* __restrict__ bqv, float* __restrict__ hidden)
{
    const int h  = blockIdx.y;
    const int r0 = blockIdx.x * 64;      // bn tile (b constant within tile)
    const int b  = r0 >> 8;
    __shared__ float As[64][17];
    __shared__ float Bs[16][68];
    const int t  = threadIdx.x;
    const int tr = t >> 4, tc = t & 15;
    const int sr = t >> 2, sk4 = (t & 3) << 2;
    const int bkr = t >> 4, bj4 = (t & 15) << 2;
    float acc[4][4] = {};

    // phase 1: K over m — A = attn rows, B = v
    for (int k0 = 0; k0 < 256; k0 += 16) {
        float4 a4 = *reinterpret_cast<const float4*>(
            &attn[(size_t)((b * 4 + h) * 256 + ((r0 + sr) & 255)) * 256 + k0 + sk4]);
        float4 b4 = *reinterpret_cast<const float4*>(
            &qkvp[(size_t)(1024 + b * 256 + k0 + bkr) * 256 + h * 64 + bj4]);
        As[sr][sk4 + 0] = a4.x; As[sr][sk4 + 1] = a4.y; As[sr][sk4 + 2] = a4.z; As[sr][sk4 + 3] = a4.w;
        Bs[bkr][bj4 + 0] = b4.x; Bs[bkr][bj4 + 1] = b4.y; Bs[bkr][bj4 + 2] = b4.z; Bs[bkr][bj4 + 3] = b4.w;
        __syncthreads();
        #pragma unroll
        for (int k = 0; k < 16; ++k) {
            float a[4], bbv[4];
            #pragma unroll
            for (int i = 0; i < 4; ++i) a[i] = As[tr * 4 + i][k];
            #pragma unroll
            for (int j = 0; j < 4; ++j) bbv[j] = Bs[k][tc * 4 + j];
            #pragma unroll
            for (int i = 0; i < 4; ++i)
                #pragma unroll
                for (int j = 0; j < 4; ++j)
                    acc[i][j] = fmaf(a[i], bbv[j], acc[i][j]);
        }
        __syncthreads();
    }
    // phase 2: K over d — A = Afull, B = Wqv
    for (int k0 = 0; k0 < 256; k0 += 16) {
        float4 a4 = *reinterpret_cast<const float4*>(
            &Afull[(size_t)(r0 + sr) * 1024 + h * 256 + k0 + sk4]);
        float4 b4 = *reinterpret_cast<const float4*>(
            &Wqv[(size_t)(k0 + bkr) * 256 + h * 64 + bj4]);
        As[sr][sk4 + 0] = a4.x; As[sr][sk4 + 1] = a4.y; As[sr][sk4 + 2] = a4.z; As[sr][sk4 + 3] = a4.w;
        Bs[bkr][bj4 + 0] = b4.x; Bs[bkr][bj4 + 1] = b4.y; Bs[bkr][bj4 + 2] = b4.z; Bs[bkr][bj4 + 3] = b4.w;
        __syncthreads();
        #pragma unroll
        for (int k = 0; k < 16; ++k) {
            float a[4], bbv[4];
            #pragma unroll
            for (int i = 0; i < 4; ++i) a[i] = As[tr * 4 + i][k];
            #pragma unroll
            for (int j = 0; j < 4; ++j) bbv[j] = Bs[k][tc * 4 + j];
            #pragma unroll
            for (int i = 0; i < 4; ++i)
                #pragma unroll
                for (int j = 0; j < 4; ++j)
                    acc[i][j] = fmaf(a[i], bbv[j], acc[i][j]);
        }
        __syncthreads();
    }
    #pragma unroll
    for (int i = 0; i < 4; ++i) {
        const int r = r0 + tr * 4 + i;
        #pragma unroll
        for (int j = 0; j < 4; ++j) {
            const int cj = h * 64 + tc * 4 + j;
            hidden[(size_t)r * 256 + cj] = acc[i][j] + bqv[cj];
        }
    }
}

extern "C" void kernel_launch(void* const* d_in, const int* in_sizes, int n_in,
                              void* d_out, int out_size, void* d_ws, size_t ws_size,
                              hipStream_t stream) {
    (void)in_sizes; (void)n_in; (void)out_size; (void)ws_size;
    const float* q_tok  = (const float*)d_in[0];
    const float* k_tok  = (const float*)d_in[1];
    const float* v_tok  = (const float*)d_in[2];
    const float* qk_emb = (const float*)d_in[3];
    const float* qv_emb = (const float*)d_in[4];
    const float* Wq  = (const float*)d_in[5];   const float* bq  = (const float*)d_in[6];
    const float* Wk  = (const float*)d_in[7];   const float* bk  = (const float*)d_in[8];
    const float* Wv  = (const float*)d_in[9];   const float* bv  = (const float*)d_in[10];
    const float* Wqk = (const float*)d_in[11];  /* bqk softmax-invariant */
    const float* Wqv = (const float*)d_in[13];  const float* bqv = (const float*)d_in[14];

    float* ws    = (float*)d_ws;
    float* qkvp  = ws;                      // 1536*256  = 393216
    float* qW    = ws + 393216;             // 512*1024  = 524288
    float* Sqk   = ws + 917504;             // 2048*256  = 524288
    float* Sg    = ws + 1441792;            // 2048*256  = 524288
    float* stats = ws + 1966080;            // 2048*8    = 16384
    float* Aq    = ws + 1982464;            // 2048*1024 = 2097152
    float* Afull = ws + 4079616;            // 512*1024  = 524288

    float* hidden = (float*)d_out;
    float* attn   = (float*)d_out + BB * NN * CC;

    proj_gemm    <<<dim3(24, 4),   256, 0, stream>>>(q_tok, k_tok, v_tok, Wq, bq, Wk, bk, Wv, bv, qkvp);
    qw_gemm      <<<dim3(8, 4, 4), 256, 0, stream>>>(qkvp, Wqk, qW);
    qk_gemm      <<<dim3(4, 4, 8), 256, 0, stream>>>(qkvp, Sqk);
    stream_kernel<<<dim3(512, 4),  256, 0, stream>>>(qk_emb, qv_emb, qW, Sqk, Sg, stats, Aq);
    merge_kernel <<<512,           256, 0, stream>>>(Sg, stats, Aq, attn, Afull);
    out_gemm     <<<dim3(8, 4),    256, 0, stream>>>(qkvp, attn, Afull, Wqv, bqv, hidden);
}

// Round 13
// 86.071 us; speedup vs baseline: 1.4716x; 1.4716x over previous
//
#include <hip/hip_runtime.h>

#define BB 2
#define NN 256
#define CC 256

__device__ __forceinline__ float dot4acc(float4 e, float4 w, float s) {
    s = fmaf(e.x, w.x, s); s = fmaf(e.y, w.y, s);
    s = fmaf(e.z, w.z, s); s = fmaf(e.w, w.w, s);
    return s;
}

// ---------------------------------------------------------------------------
// K1: fused q/k/v projections.  rows 0..511 = q (B*N), 512..1023 = k, 1024..1535 = v
// ---------------------------------------------------------------------------
__global__ __launch_bounds__(256) void proj_gemm(
    const float* __restrict__ q_tok, const float* __restrict__ k_tok, const float* __restrict__ v_tok,
    const float* __restrict__ Wq, const float* __restrict__ bq,
    const float* __restrict__ Wk, const float* __restrict__ bk,
    const float* __restrict__ Wv, const float* __restrict__ bv,
    float* __restrict__ out)
{
    const int row0 = blockIdx.x * 64;
    const int col0 = blockIdx.y * 64;
    const int seg  = row0 >> 9;
    const float* A    = seg == 0 ? q_tok : (seg == 1 ? k_tok : v_tok);
    const float* W    = seg == 0 ? Wq    : (seg == 1 ? Wk    : Wv);
    const float* bias = seg == 0 ? bq    : (seg == 1 ? bk    : bv);
    const int ar0 = row0 & 511;

    __shared__ float As[64][17];
    __shared__ float Bs[16][68];
    const int t  = threadIdx.x;
    const int tr = t >> 4, tc = t & 15;
    float acc[4][4] = {};

    const int sr  = t >> 2, sk4 = (t & 3) << 2;
    const int bkr = t >> 4, bj4 = (t & 15) << 2;

    for (int k0 = 0; k0 < 256; k0 += 16) {
        float4 a4 = *reinterpret_cast<const float4*>(&A[(ar0 + sr) * 256 + k0 + sk4]);
        float4 b4 = *reinterpret_cast<const float4*>(&W[(k0 + bkr) * 256 + col0 + bj4]);
        As[sr][sk4 + 0] = a4.x; As[sr][sk4 + 1] = a4.y; As[sr][sk4 + 2] = a4.z; As[sr][sk4 + 3] = a4.w;
        Bs[bkr][bj4 + 0] = b4.x; Bs[bkr][bj4 + 1] = b4.y; Bs[bkr][bj4 + 2] = b4.z; Bs[bkr][bj4 + 3] = b4.w;
        __syncthreads();
        #pragma unroll
        for (int k = 0; k < 16; ++k) {
            float a[4], bbv[4];
            #pragma unroll
            for (int i = 0; i < 4; ++i) a[i] = As[tr * 4 + i][k];
            #pragma unroll
            for (int j = 0; j < 4; ++j) bbv[j] = Bs[k][tc * 4 + j];
            #pragma unroll
            for (int i = 0; i < 4; ++i)
                #pragma unroll
                for (int j = 0; j < 4; ++j)
                    acc[i][j] = fmaf(a[i], bbv[j], acc[i][j]);
        }
        __syncthreads();
    }
    #pragma unroll
    for (int i = 0; i < 4; ++i) {
        const int r = row0 + tr * 4 + i;
        #pragma unroll
        for (int j = 0; j < 4; ++j) {
            const int cj = col0 + tc * 4 + j;
            out[r * 256 + cj] = acc[i][j] + bias[cj];
        }
    }
}

// ---------------------------------------------------------------------------
// K2: pre_gemm — fused qw_gemm + qk_gemm (identical tile bodies, role split).
// id < 128:  qW[bn][h][d]  = sum_c qp[bn][h*64+c]   * Wqk[d][h*64+c]
// id >= 128: Sqk[b,h,n,m]  = sum_c q[b,n,h*64+c]    * k[b,m,h*64+c]
// ---------------------------------------------------------------------------
__global__ __launch_bounds__(256) void pre_gemm(
    const float* __restrict__ qp, const float* __restrict__ Wqk,
    float* __restrict__ qW, float* __restrict__ Sqk)
{
    const int id = blockIdx.x;
    const float *Abase, *Bbase;
    float* outp;
    size_t outbase;
    int orstride;

    if (id < 128) {
        const int x = id & 7, y = (id >> 3) & 3, z = id >> 5;   // 8 x 4 x 4
        const int row0 = x * 64, d0 = y * 64, h = z;
        Abase = qp  + (size_t)row0 * 256 + h * 64;
        Bbase = Wqk + (size_t)d0 * 256 + h * 64;
        outp = qW; outbase = (size_t)(row0 * 4 + h) * 256 + d0; orstride = 1024;
    } else {
        const int id2 = id - 128;
        const int x = id2 & 3, y = (id2 >> 2) & 3, z = id2 >> 4; // 4 x 4 x 8
        const int b = z >> 2, h = z & 3;
        const int n0 = x * 64, m0 = y * 64;
        Abase = qp + (size_t)(b * 256 + n0) * 256 + h * 64;
        Bbase = qp + (size_t)(512 + b * 256 + m0) * 256 + h * 64;
        outp = Sqk; outbase = ((size_t)((b * 4 + h) * 256 + n0)) * 256 + m0; orstride = 256;
    }

    __shared__ float As[64][17];
    __shared__ float Bs[16][68];
    const int t  = threadIdx.x;
    const int tr = t >> 4, tc = t & 15;
    float acc[4][4] = {};
    const int sr = t >> 2, sc4 = (t & 3) << 2;

    for (int k0 = 0; k0 < 64; k0 += 16) {
        float4 a4 = *reinterpret_cast<const float4*>(&Abase[(size_t)sr * 256 + k0 + sc4]);
        float4 b4 = *reinterpret_cast<const float4*>(&Bbase[(size_t)sr * 256 + k0 + sc4]);
        As[sr][sc4 + 0] = a4.x; As[sr][sc4 + 1] = a4.y; As[sr][sc4 + 2] = a4.z; As[sr][sc4 + 3] = a4.w;
        Bs[sc4 + 0][sr] = b4.x; Bs[sc4 + 1][sr] = b4.y; Bs[sc4 + 2][sr] = b4.z; Bs[sc4 + 3][sr] = b4.w;
        __syncthreads();
        #pragma unroll
        for (int k = 0; k < 16; ++k) {
            float a[4], bbv[4];
            #pragma unroll
            for (int i = 0; i < 4; ++i) a[i] = As[tr * 4 + i][k];
            #pragma unroll
            for (int j = 0; j < 4; ++j) bbv[j] = Bs[k][tc * 4 + j];
            #pragma unroll
            for (int i = 0; i < 4; ++i)
                #pragma unroll
                for (int j = 0; j < 4; ++j)
                    acc[i][j] = fmaf(a[i], bbv[j], acc[i][j]);
        }
        __syncthreads();
    }
    #pragma unroll
    for (int i = 0; i < 4; ++i)
        #pragma unroll
        for (int j = 0; j < 4; ++j)
            outp[outbase + (size_t)(tr * 4 + i) * orstride + tc * 4 + j] = acc[i][j];
}

// ---------------------------------------------------------------------------
// K3: mega4 — online-softmax streaming with 2-deep register ping-pong
// (round-9 verified best: 91.6 us total).
// ---------------------------------------------------------------------------

#define S1_LOAD(E00,E01,E02,E03,E10,E11,E12,E13, MB)                          \
    do {                                                                      \
        const float* _r0 = qk_emb + (size_t)(bn * 256 + (MB) + lr) * 256 + lq * 4; \
        const float* _r1 = _r0 + 1024;                                        \
        E00 = *reinterpret_cast<const float4*>(_r0);                          \
        E01 = *reinterpret_cast<const float4*>(_r0 + 64);                     \
        E02 = *reinterpret_cast<const float4*>(_r0 + 128);                    \
        E03 = *reinterpret_cast<const float4*>(_r0 + 192);                    \
        E10 = *reinterpret_cast<const float4*>(_r1);                          \
        E11 = *reinterpret_cast<const float4*>(_r1 + 64);                     \
        E12 = *reinterpret_cast<const float4*>(_r1 + 128);                    \
        E13 = *reinterpret_cast<const float4*>(_r1 + 192);                    \
    } while (0)

#define S1_COMP(E00,E01,E02,E03,E10,E11,E12,E13, MB)                          \
    do {                                                                      \
        const int _m0 = (MB) + lr;                                            \
        float p0[4], p1[4];                                                   \
        _Pragma("unroll")                                                     \
        for (int hh = 0; hh < 4; ++hh) {                                      \
            const float4 w0 = *reinterpret_cast<const float4*>(&qWs[hh * 256 + lq * 4]);        \
            const float4 w1 = *reinterpret_cast<const float4*>(&qWs[hh * 256 + 64 + lq * 4]);   \
            const float4 w2 = *reinterpret_cast<const float4*>(&qWs[hh * 256 + 128 + lq * 4]);  \
            const float4 w3 = *reinterpret_cast<const float4*>(&qWs[hh * 256 + 192 + lq * 4]);  \
            float s0 = 0.f, s1 = 0.f;                                         \
            s0 = dot4acc(E00, w0, s0); s0 = dot4acc(E01, w1, s0);             \
            s0 = dot4acc(E02, w2, s0); s0 = dot4acc(E03, w3, s0);             \
            s1 = dot4acc(E10, w0, s1); s1 = dot4acc(E11, w1, s1);             \
            s1 = dot4acc(E12, w2, s1); s1 = dot4acc(E13, w3, s1);             \
            p0[hh] = s0; p1[hh] = s1;                                         \
        }                                                                     \
        _Pragma("unroll")                                                     \
        for (int hh = 0; hh < 4; ++hh) {                                      \
            p0[hh] += __shfl_xor(p0[hh], 1); p1[hh] += __shfl_xor(p1[hh], 1); \
            p0[hh] += __shfl_xor(p0[hh], 2); p1[hh] += __shfl_xor(p1[hh], 2); \
            p0[hh] += __shfl_xor(p0[hh], 4); p1[hh] += __shfl_xor(p1[hh], 4); \
            p0[hh] += __shfl_xor(p0[hh], 8); p1[hh] += __shfl_xor(p1[hh], 8); \
        }                                                                     \
        if (lq == 0) {                                                        \
            _Pragma("unroll")                                                 \
            for (int hh = 0; hh < 4; ++hh) {                                  \
                Ssc[hh * 256 + _m0]     = p0[hh];                             \
                Ssc[hh * 256 + _m0 + 4] = p1[hh];                             \
            }                                                                 \
        }                                                                     \
    } while (0)

#define S2_LOAD(F0,F1,F2,F3,F4,F5,F6,F7, MB)                                  \
    do {                                                                      \
        const float* _rb = qv_emb + (size_t)(bn * 256 + (MB)) * 256 + l * 4;  \
        F0 = *reinterpret_cast<const float4*>(_rb);                           \
        F1 = *reinterpret_cast<const float4*>(_rb + 256);                     \
        F2 = *reinterpret_cast<const float4*>(_rb + 512);                     \
        F3 = *reinterpret_cast<const float4*>(_rb + 768);                     \
        F4 = *reinterpret_cast<const float4*>(_rb + 1024);                    \
        F5 = *reinterpret_cast<const float4*>(_rb + 1280);                    \
        F6 = *reinterpret_cast<const float4*>(_rb + 1536);                    \
        F7 = *reinterpret_cast<const float4*>(_rb + 1792);                    \
    } while (0)

#define S2_ONE(F, RIDX)                                                       \
    do {                                                                      \
        _Pragma("unroll")                                                     \
        for (int hh = 0; hh < 4; ++hh) {                                      \
            const float a = attn_s[hh * 256 + (RIDX)];                        \
            acc[hh].x = fmaf(a, F.x, acc[hh].x);                              \
            acc[hh].y = fmaf(a, F.y, acc[hh].y);                              \
            acc[hh].z = fmaf(a, F.z, acc[hh].z);                              \
            acc[hh].w = fmaf(a, F.w, acc[hh].w);                              \
        }                                                                     \
    } while (0)

#define S2_COMP(F0,F1,F2,F3,F4,F5,F6,F7, MB)                                  \
    do {                                                                      \
        S2_ONE(F0, (MB) + 0); S2_ONE(F1, (MB) + 1);                           \
        S2_ONE(F2, (MB) + 2); S2_ONE(F3, (MB) + 3);                           \
        S2_ONE(F4, (MB) + 4); S2_ONE(F5, (MB) + 5);                           \
        S2_ONE(F6, (MB) + 6); S2_ONE(F7, (MB) + 7);                           \
    } while (0)

__global__ __launch_bounds__(512, 4) void mega4(
    const float* __restrict__ qk_emb, const float* __restrict__ qv_emb,
    const float* __restrict__ qkvp, const float* __restrict__ qW,
    const float* __restrict__ Sqk, const float* __restrict__ Wqv,
    const float* __restrict__ bqv,
    float* __restrict__ attn_out, float* __restrict__ hidden)
{
    const int bn = blockIdx.x;
    const int b  = bn >> 8, n = bn & 255;
    const int t  = threadIdx.x;
    const int w  = t >> 6, l = t & 63;

    __shared__ float qWs[1024];          // [h][d]
    __shared__ float SqkL[1024];         // [h][m]  raw q.k
    __shared__ float Ssc[1024];          // [h][m]  raw pair scores
    __shared__ float attn_s[1024];       // [h][m]  e -> later normalized attn
    __shared__ float Ap[4096];           // [16][256] A partials; [4][256] after reduce
    __shared__ float stage[16][256];
    __shared__ float pr[2][256];
    __shared__ float mxs[8][4], sums[8][4], scl[8][4];

    // ---- stage qW (contiguous 4 KB) ----
    if (t < 256)
        *reinterpret_cast<float4*>(&qWs[t * 4]) =
            *reinterpret_cast<const float4*>(&qW[(size_t)bn * 1024 + t * 4]);
    __syncthreads();

    const int lq = l & 15, lr = l >> 4, li = l & 31;
    const int mw = w * 32;

    // ================= wave-independent streaming (no barriers) =============
    // this wave's Sqk segment
    if (l < 32) {
        #pragma unroll
        for (int h = 0; h < 4; ++h)
            SqkL[h * 256 + mw + li] =
                Sqk[(size_t)((b * 4 + h) * 256 + n) * 256 + mw + li];
    }

    // ---- sub-pass 1: pair scores, 2-deep ping-pong over 4 batches of 8 rows
    {
        float4 a00, a01, a02, a03, a10, a11, a12, a13;
        float4 b00, b01, b02, b03, b10, b11, b12, b13;
        S1_LOAD(a00,a01,a02,a03,a10,a11,a12,a13, mw + 0);
        S1_LOAD(b00,b01,b02,b03,b10,b11,b12,b13, mw + 8);
        S1_COMP(a00,a01,a02,a03,a10,a11,a12,a13, mw + 0);
        S1_LOAD(a00,a01,a02,a03,a10,a11,a12,a13, mw + 16);
        S1_COMP(b00,b01,b02,b03,b10,b11,b12,b13, mw + 8);
        S1_LOAD(b00,b01,b02,b03,b10,b11,b12,b13, mw + 24);
        S1_COMP(a00,a01,a02,a03,a10,a11,a12,a13, mw + 16);
        S1_COMP(b00,b01,b02,b03,b10,b11,b12,b13, mw + 24);
    }

    // wave-local stats: max + sum(exp) over this wave's 32 rows, per head
    float mxw[4], smw[4];
    #pragma unroll
    for (int h = 0; h < 4; ++h) {
        const float sc = (Ssc[h * 256 + mw + li] + SqkL[h * 256 + mw + li]) * 0.125f;
        float mx = sc;
        #pragma unroll
        for (int mask = 16; mask >= 1; mask >>= 1) mx = fmaxf(mx, __shfl_xor(mx, mask));
        const float e = __expf(sc - mx);
        attn_s[h * 256 + mw + li] = e;   // both 32-halves write identical value
        float sm = e;
        #pragma unroll
        for (int mask = 16; mask >= 1; mask >>= 1) sm += __shfl_xor(sm, mask);
        mxw[h] = mx; smw[h] = sm;
    }
    if (l == 0) {
        #pragma unroll
        for (int h = 0; h < 4; ++h) { mxs[w][h] = mxw[h]; sums[w][h] = smw[h]; }
    }

    // ---- sub-pass 2: A_w[h][d] += e * qv, 2-deep ping-pong ----
    float4 acc[4];
    #pragma unroll
    for (int hh = 0; hh < 4; ++hh) acc[hh] = make_float4(0.f, 0.f, 0.f, 0.f);
    {
        float4 f0, f1, f2, f3, f4, f5, f6, f7;
        float4 g0, g1, g2, g3, g4, g5, g6, g7;
        S2_LOAD(f0,f1,f2,f3,f4,f5,f6,f7, mw + 0);
        S2_LOAD(g0,g1,g2,g3,g4,g5,g6,g7, mw + 8);
        S2_COMP(f0,f1,f2,f3,f4,f5,f6,f7, mw + 0);
        S2_LOAD(f0,f1,f2,f3,f4,f5,f6,f7, mw + 16);
        S2_COMP(g0,g1,g2,g3,g4,g5,g6,g7, mw + 8);
        S2_LOAD(g0,g1,g2,g3,g4,g5,g6,g7, mw + 24);
        S2_COMP(f0,f1,f2,f3,f4,f5,f6,f7, mw + 16);
        S2_COMP(g0,g1,g2,g3,g4,g5,g6,g7, mw + 24);
    }
    // ======================= end barrier-free section =======================
    __syncthreads();   // B1: all stats + e's final

    // global merge: scl[w][h] = exp(mx_w - mx_g) / sum_g   (exact softmax)
    if (t < 4) {
        const int h = t;
        float mg = mxs[0][h];
        #pragma unroll
        for (int ww = 1; ww < 8; ++ww) mg = fmaxf(mg, mxs[ww][h]);
        float sr[8]; float sg = 0.f;
        #pragma unroll
        for (int ww = 0; ww < 8; ++ww) { sr[ww] = __expf(mxs[ww][h] - mg); sg += sums[ww][h] * sr[ww]; }
        const float inv = 1.f / sg;
        #pragma unroll
        for (int ww = 0; ww < 8; ++ww) scl[ww][h] = sr[ww] * inv;
    }
    __syncthreads();   // B2: scl ready

    // normalize attn (LDS in place) + write attn output
    {
        const int h = t >> 7, j = t & 127;
        float* ao = attn_out + (size_t)((b * 4 + h) * 256 + n) * 256;
        #pragma unroll
        for (int rep = 0; rep < 2; ++rep) {
            const int jj = j + rep * 128;
            const float a = attn_s[h * 256 + jj] * scl[jj >> 5][h];
            attn_s[h * 256 + jj] = a;
            ao[jj] = a;
        }
    }
    // scaled A partial reduction into Ap
    if (w < 4) {
        #pragma unroll
        for (int hh = 0; hh < 4; ++hh) {
            const float s = scl[w][hh];
            float4 v = acc[hh];
            v.x *= s; v.y *= s; v.z *= s; v.w *= s;
            *reinterpret_cast<float4*>(&Ap[(w * 4 + hh) * 256 + l * 4]) = v;
        }
    }
    __syncthreads();   // B3
    if (w >= 4) {
        #pragma unroll
        for (int hh = 0; hh < 4; ++hh) {
            const float s = scl[w][hh];
            float4* p = reinterpret_cast<float4*>(&Ap[((w - 4) * 4 + hh) * 256 + l * 4]);
            float4 o = *p;
            o.x = fmaf(acc[hh].x, s, o.x); o.y = fmaf(acc[hh].y, s, o.y);
            o.z = fmaf(acc[hh].z, s, o.z); o.w = fmaf(acc[hh].w, s, o.w);
            *p = o;
        }
    }
    __syncthreads();   // B4
    #pragma unroll
    for (int i = 0; i < 2; ++i) {
        const int idx = t + i * 512;
        const int hh = idx >> 8, d = idx & 255;
        Ap[hh * 256 + d] = Ap[hh * 256 + d] + Ap[(4 + hh) * 256 + d]
                         + Ap[(8 + hh) * 256 + d] + Ap[(12 + hh) * 256 + d];
    }

    // ---- phase 4: hidden = attn@v + A@Wqv + bqv, register-double-buffered ----
    {
        const int c = t & 255, half = t >> 8, hc = c >> 6;
        const int fr0 = t >> 6, fc0 = (t & 63) * 4;
        const int fr1 = fr0 + 8;
        const float* vbase = qkvp + (size_t)(1024 + b * 256) * 256;
        float4 ra = *reinterpret_cast<const float4*>(&vbase[(size_t)fr0 * 256 + fc0]);
        float4 rb = *reinterpret_cast<const float4*>(&vbase[(size_t)fr1 * 256 + fc0]);
        float hv = 0.f;
        for (int mt = 0; mt < 16; ++mt) {
            __syncthreads();
            *reinterpret_cast<float4*>(&stage[fr0][fc0]) = ra;
            *reinterpret_cast<float4*>(&stage[fr1][fc0]) = rb;
            if (mt < 15) {
                ra = *reinterpret_cast<const float4*>(&vbase[(size_t)((mt + 1) * 16 + fr0) * 256 + fc0]);
                rb = *reinterpret_cast<const float4*>(&vbase[(size_t)((mt + 1) * 16 + fr1) * 256 + fc0]);
            } else {
                ra = *reinterpret_cast<const float4*>(&Wqv[(size_t)fr0 * 256 + fc0]);
                rb = *reinterpret_cast<const float4*>(&Wqv[(size_t)fr1 * 256 + fc0]);
            }
            __syncthreads();
            #pragma unroll
            for (int r = 0; r < 8; ++r)
                hv = fmaf(attn_s[hc * 256 + mt * 16 + half * 8 + r], stage[half * 8 + r][c], hv);
        }
        for (int dt = 0; dt < 16; ++dt) {
            __syncthreads();
            *reinterpret_cast<float4*>(&stage[fr0][fc0]) = ra;
            *reinterpret_cast<float4*>(&stage[fr1][fc0]) = rb;
            if (dt < 15) {
                ra = *reinterpret_cast<const float4*>(&Wqv[(size_t)((dt + 1) * 16 + fr0) * 256 + fc0]);
                rb = *reinterpret_cast<const float4*>(&Wqv[(size_t)((dt + 1) * 16 + fr1) * 256 + fc0]);
            }
            __syncthreads();
            #pragma unroll
            for (int r = 0; r < 8; ++r)
                hv = fmaf(Ap[hc * 256 + dt * 16 + half * 8 + r], stage[half * 8 + r][c], hv);
        }
        pr[half][c] = hv;
    }
    __syncthreads();
    if (t < 256)
        hidden[(size_t)bn * 256 + t] = pr[0][t] + pr[1][t] + bqv[t];
}

extern "C" void kernel_launch(void* const* d_in, const int* in_sizes, int n_in,
                              void* d_out, int out_size, void* d_ws, size_t ws_size,
                              hipStream_t stream) {
    (void)in_sizes; (void)n_in; (void)out_size; (void)ws_size;
    const float* q_tok  = (const float*)d_in[0];
    const float* k_tok  = (const float*)d_in[1];
    const float* v_tok  = (const float*)d_in[2];
    const float* qk_emb = (const float*)d_in[3];
    const float* qv_emb = (const float*)d_in[4];
    const float* Wq  = (const float*)d_in[5];   const float* bq  = (const float*)d_in[6];
    const float* Wk  = (const float*)d_in[7];   const float* bk  = (const float*)d_in[8];
    const float* Wv  = (const float*)d_in[9];   const float* bv  = (const float*)d_in[10];
    const float* Wqk = (const float*)d_in[11];  /* bqk softmax-invariant */
    const float* Wqv = (const float*)d_in[13];  const float* bqv = (const float*)d_in[14];

    float* ws   = (float*)d_ws;
    float* qkvp = ws;                      // 1536*256 = 393216
    float* qW   = ws + 393216;             // 512*1024 = 524288
    float* Sqk  = ws + 917504;             // 2048*256 = 524288

    float* hidden = (float*)d_out;
    float* attn   = (float*)d_out + BB * NN * CC;

    proj_gemm<<<dim3(24, 4), 256, 0, stream>>>(q_tok, k_tok, v_tok, Wq, bq, Wk, bk, Wv, bv, qkvp);
    pre_gemm <<<256,         256, 0, stream>>>(qkvp, Wqk, qW, Sqk);
    mega4    <<<512,         512, 0, stream>>>(qk_emb, qv_emb, qkvp, qW, Sqk, Wqv, bqv, attn, hidden);
}